// Round 1
// baseline (3691.083 us; speedup 1.0000x reference)
//
#include <hip/hip_runtime.h>

// ---------------------------------------------------------------------------
// MRT12: 8-layer {keygen GEMM -> tanh/sigmoid -> lerp-scan -> dwconv3 -> MLP
// -> rmsnorm -> residual(+plastic)} -> final norms -> tied LM head -> std fix.
// B=2,S=1024,D=1024,L=8,V=32000. fp32 in/out.
// GEMMs: bf16x2-split MFMA (Ah*Bh + Ah*Bl + Al*Bh, fp32 accum) for layers,
// single fp16 MFMA for LM head. Everything else fp32.
// ---------------------------------------------------------------------------

using short8 = __attribute__((ext_vector_type(8))) short;
using bf16x8 = __attribute__((ext_vector_type(8))) __bf16;
using half8  = __attribute__((ext_vector_type(8))) _Float16;
using f32x4  = __attribute__((ext_vector_type(4))) float;

#define DEVI __device__ __forceinline__

DEVI unsigned short f2bf(float x) {            // RNE float -> bf16 bits
  union { float f; unsigned u; } v; v.f = x;
  unsigned r = v.u + 0x7fffu + ((v.u >> 16) & 1u);
  return (unsigned short)(r >> 16);
}
DEVI float bf2f(unsigned short h) {
  union { float f; unsigned u; } v; v.u = ((unsigned)h) << 16;
  return v.f;
}
DEVI float sigm(float x) { return 1.0f / (1.0f + expf(-x)); }

DEVI float block_sum256(float v) {             // 256-thread block sum
  #pragma unroll
  for (int o = 32; o > 0; o >>= 1) v += __shfl_down(v, o, 64);
  __shared__ float sm[4];
  if ((threadIdx.x & 63) == 0) sm[threadIdx.x >> 6] = v;
  __syncthreads();
  float t = sm[0] + sm[1] + sm[2] + sm[3];
  __syncthreads();
  return t;
}

// ---------------------------------------------------------------------------
// GEMM: C[M,N] = sum_p A_p[M,K] * B_p[N,K]^T   (B stored N-major, "B^T" form)
// 128x128 tile, BK=32, 4 waves of 64x64, 16x16x32 MFMA. Reg-staged LDS.
// EPI: 0 raw fp32; 1 keygen (tanh*pi | sigmoid); 2 +bias,silu,bf16-split out;
//      3 +bias fp32; 4 xbuf += C.
// ---------------------------------------------------------------------------
template<int NP, int FP16, int EPI>
__global__ __launch_bounds__(256) void gemm_bt(
    const unsigned short* __restrict__ A0, const unsigned short* __restrict__ A1,
    const unsigned short* __restrict__ A2,
    const unsigned short* __restrict__ B0, const unsigned short* __restrict__ B1,
    const unsigned short* __restrict__ B2,
    int M, int N, int K,
    float* __restrict__ outF,
    unsigned short* __restrict__ outH, unsigned short* __restrict__ outL,
    const float* __restrict__ bias, float* __restrict__ xbuf, int halfN)
{
  __shared__ __align__(16) unsigned short As[128 * 32];
  __shared__ __align__(16) unsigned short Bs[128 * 32];
  const int tid  = threadIdx.x;
  const int lane = tid & 63, wid = tid >> 6;
  const int wr = wid >> 1, wc = wid & 1;
  const int m0 = blockIdx.y * 128, n0 = blockIdx.x * 128;
  const int srow = tid >> 2;            // 0..63 staging row
  const int scol = (tid & 3) * 8;       // staging col (elements)

  f32x4 acc[4][4] = {};

  const unsigned short* Ap[3] = {A0, A1, A2};
  const unsigned short* Bp[3] = {B0, B1, B2};

  #pragma unroll
  for (int p = 0; p < NP; ++p) {
    const unsigned short* __restrict__ A = Ap[p];
    const unsigned short* __restrict__ B = Bp[p];
    for (int k0 = 0; k0 < K; k0 += 32) {
      __syncthreads();
      short8 a0 = *(const short8*)&A[(size_t)(m0 + srow     ) * K + k0 + scol];
      short8 a1 = *(const short8*)&A[(size_t)(m0 + srow + 64) * K + k0 + scol];
      short8 b0 = *(const short8*)&B[(size_t)(n0 + srow     ) * K + k0 + scol];
      short8 b1 = *(const short8*)&B[(size_t)(n0 + srow + 64) * K + k0 + scol];
      *(short8*)&As[(srow     ) * 32 + scol] = a0;
      *(short8*)&As[(srow + 64) * 32 + scol] = a1;
      *(short8*)&Bs[(srow     ) * 32 + scol] = b0;
      *(short8*)&Bs[(srow + 64) * 32 + scol] = b1;
      __syncthreads();
      const int kq = (lane >> 4) * 8;
      short8 af[4], bfr[4];
      #pragma unroll
      for (int i = 0; i < 4; ++i)
        af[i] = *(const short8*)&As[(wr * 64 + i * 16 + (lane & 15)) * 32 + kq];
      #pragma unroll
      for (int j = 0; j < 4; ++j)
        bfr[j] = *(const short8*)&Bs[(wc * 64 + j * 16 + (lane & 15)) * 32 + kq];
      #pragma unroll
      for (int i = 0; i < 4; ++i)
        #pragma unroll
        for (int j = 0; j < 4; ++j) {
          if constexpr (FP16)
            acc[i][j] = __builtin_amdgcn_mfma_f32_16x16x32_f16(
                __builtin_bit_cast(half8, af[i]), __builtin_bit_cast(half8, bfr[j]),
                acc[i][j], 0, 0, 0);
          else
            acc[i][j] = __builtin_amdgcn_mfma_f32_16x16x32_bf16(
                __builtin_bit_cast(bf16x8, af[i]), __builtin_bit_cast(bf16x8, bfr[j]),
                acc[i][j], 0, 0, 0);
        }
    }
  }

  // epilogue: lane holds D[row=(lane>>4)*4+r][col=lane&15] per 16x16 frag (m89)
  #pragma unroll
  for (int i = 0; i < 4; ++i) {
    const int rbase = m0 + wr * 64 + i * 16 + ((lane >> 4) << 2);
    #pragma unroll
    for (int j = 0; j < 4; ++j) {
      const int col = n0 + wc * 64 + j * 16 + (lane & 15);
      #pragma unroll
      for (int r = 0; r < 4; ++r) {
        float c = acc[i][j][r];
        const size_t idx = (size_t)(rbase + r) * N + col;
        if constexpr (EPI == 0) {
          outF[idx] = c;
        } else if constexpr (EPI == 1) {
          outF[idx] = (col < halfN) ? (tanhf(c) * 3.14159265358979323846f)
                                    : sigm(c);
        } else if constexpr (EPI == 2) {
          c += bias[col];
          float s = c * sigm(c);                 // silu
          unsigned short hi = f2bf(s);
          outH[idx] = hi; outL[idx] = f2bf(s - bf2f(hi));
        } else if constexpr (EPI == 3) {
          outF[idx] = c + bias[col];
        } else {                                  // EPI == 4
          xbuf[idx] += c;
        }
      }
    }
  }
}

// ---------------------------------------------------------------------------
// lerp scan: h_t = (1-a_t) h_{t-1} + a_t v_t, per channel (b,d), over s.
// va[b,s,0:D]=v, va[b,s,D:2D]=a (precomputed by G1 epilogue).
// Block: 16 channels x 16 chunks of 64 steps; pass1 totals, LDS prefix, pass2.
// ---------------------------------------------------------------------------
__global__ __launch_bounds__(256) void scan_kernel(
    const float* __restrict__ va, float* __restrict__ h, int S, int D)
{
  const int dl = threadIdx.x & 15;
  const int c  = threadIdx.x >> 4;           // chunk 0..15
  const int ch = blockIdx.x * 16 + dl;       // global channel
  const int b = ch / D, d = ch % D;
  const float* vb = va + (size_t)b * S * 2 * D + d;
  const float* ab = vb + D;
  const int CH = S / 16;                     // 64 steps per chunk
  float Ar = 1.f, Br = 0.f;
  for (int t = 0; t < CH; ++t) {
    int s = c * CH + t;
    float v = vb[(size_t)s * 2 * D];
    float a = ab[(size_t)s * 2 * D];
    float na = 1.f - a;
    Ar *= na;
    Br = Br * na + a * v;
  }
  __shared__ float Asm[16][16], Bsm[16][16]; // [chunk][channel]
  Asm[c][dl] = Ar; Bsm[c][dl] = Br;
  __syncthreads();
  if (c == 0) {                               // serial 16-chunk prefix
    float run = 0.f;                          // h before chunk 0 is 0
    for (int cc = 0; cc < 16; ++cc) {
      float A_ = Asm[cc][dl], B_ = Bsm[cc][dl];
      Bsm[cc][dl] = run;                      // exclusive prefix -> h_in
      run = A_ * run + B_;
    }
  }
  __syncthreads();
  float hc = Bsm[c][dl];
  float* hb = h + (size_t)b * S * D + d;
  for (int t = 0; t < CH; ++t) {
    int s = c * CH + t;
    float v = vb[(size_t)s * 2 * D];
    float a = ab[(size_t)s * 2 * D];
    hc = hc + a * (v - hc);                   // (1-a)h + a v
    hb[(size_t)s * D] = hc;
  }
}

// z = h + (dwconv3(h) + cb); output bf16 split for next GEMM
__global__ __launch_bounds__(256) void conv_z(
    const float* __restrict__ h, const float* __restrict__ cw,
    const float* __restrict__ cb,
    unsigned short* __restrict__ zh, unsigned short* __restrict__ zl,
    int S, int D, int total)
{
  int idx = blockIdx.x * 256 + threadIdx.x;
  if (idx >= total) return;
  int d = idx % D;
  int s = (idx / D) % S;
  float h0  = h[idx];
  float hm1 = (s >= 1) ? h[idx - D]     : 0.f;
  float hm2 = (s >= 2) ? h[idx - 2 * D] : 0.f;
  float z = h0 + cb[d] + cw[d * 3 + 0] * hm2 + cw[d * 3 + 1] * hm1 + cw[d * 3 + 2] * h0;
  unsigned short hi = f2bf(z);
  zh[idx] = hi; zl[idx] = f2bf(z - bf2f(hi));
}

// delta = rmsnorm(hf)*nw; x += delta; split(mode?delta:x_new) -> oh/ol. D==1024.
__global__ __launch_bounds__(256) void rms_update(
    const float* __restrict__ hf, const float* __restrict__ nw,
    float* __restrict__ x,
    unsigned short* __restrict__ oh, unsigned short* __restrict__ ol,
    int D, int mode)
{
  const size_t base = (size_t)blockIdx.x * D;
  float vloc[4]; float ss = 0.f;
  #pragma unroll
  for (int q = 0; q < 4; ++q) {
    float v = hf[base + threadIdx.x + q * 256];
    vloc[q] = v; ss += v * v;
  }
  ss = block_sum256(ss);
  float r = 1.f / sqrtf(ss / D + 1e-8f);
  #pragma unroll
  for (int q = 0; q < 4; ++q) {
    int d = threadIdx.x + q * 256;
    float delta = vloc[q] * r * nw[d];
    float xn = x[base + d] + delta;
    x[base + d] = xn;
    float o = mode ? delta : xn;
    unsigned short hi = f2bf(o);
    oh[base + d] = hi; ol[base + d] = f2bf(o - bf2f(hi));
  }
}

// x = L2-normalize(emb[tok] + pos[s]); also bf16 split. D==1024.
__global__ __launch_bounds__(256) void embed_norm(
    const int* __restrict__ ids, const float* __restrict__ emb,
    const float* __restrict__ pos,
    float* __restrict__ x, unsigned short* __restrict__ xh,
    unsigned short* __restrict__ xl, int S, int D)
{
  const int rowi = blockIdx.x;
  const int s = rowi % S;
  const int tok = ids[rowi];
  const size_t eb = (size_t)tok * D, pb = (size_t)s * D, xb = (size_t)rowi * D;
  float vloc[4]; float ss = 0.f;
  #pragma unroll
  for (int q = 0; q < 4; ++q) {
    int d = threadIdx.x + q * 256;
    float v = emb[eb + d] + pos[pb + d];
    vloc[q] = v; ss += v * v;
  }
  ss = block_sum256(ss);
  float r = 1.f / fmaxf(sqrtf(ss), 1e-12f);
  #pragma unroll
  for (int q = 0; q < 4; ++q) {
    int d = threadIdx.x + q * 256;
    float v = vloc[q] * r;
    x[xb + d] = v;
    unsigned short hi = f2bf(v);
    xh[xb + d] = hi; xl[xb + d] = f2bf(v - bf2f(hi));
  }
}

// final double-norm: y = rmsnorm(x, w); out_f16 = y * rsqrt(mean(y^2)+eps)*0.8
__global__ __launch_bounds__(256) void final_norm(
    const float* __restrict__ x, const float* __restrict__ w,
    _Float16* __restrict__ xf, int D)
{
  const size_t base = (size_t)blockIdx.x * D;
  float s1 = 0.f, s2 = 0.f;
  float vloc[4], wloc[4];
  #pragma unroll
  for (int q = 0; q < 4; ++q) {
    int d = threadIdx.x + q * 256;
    float v = x[base + d], ww = w[d];
    vloc[q] = v; wloc[q] = ww;
    s1 += v * v; s2 += v * ww * v * ww;
  }
  s1 = block_sum256(s1);
  s2 = block_sum256(s2);
  float r1 = 1.f / sqrtf(s1 / D + 1e-8f);
  float m2 = r1 * r1 * (s2 / D);
  float r2 = 1.f / sqrtf(m2 + 1e-8f);
  float sc = r1 * r2 * 0.8f;
  #pragma unroll
  for (int q = 0; q < 4; ++q) {
    int d = threadIdx.x + q * 256;
    xf[base + d] = (_Float16)(vloc[q] * wloc[q] * sc);
  }
}

// per-row: std (ddof=1), divide by max(std,1), clip [-10,10], in place
__global__ __launch_bounds__(256) void logit_fix(float* __restrict__ out, int V)
{
  const size_t base = (size_t)blockIdx.x * V;
  float s = 0.f, q = 0.f;
  for (int j = threadIdx.x; j < V; j += 256) {
    float v = out[base + j];
    s += v; q += v * v;
  }
  s = block_sum256(s);
  q = block_sum256(q);
  float mean = s / V;
  float var = (q - (float)V * mean * mean) / (float)(V - 1);
  var = fmaxf(var, 0.f);
  float sc = 1.f / fmaxf(sqrtf(var), 1.f);
  for (int j = threadIdx.x; j < V; j += 256) {
    float v = out[base + j] * sc;
    out[base + j] = fminf(fmaxf(v, -10.f), 10.f);
  }
}

// W[K,N] fp32 -> Wh/Wl [N,K] bf16 split (transposed), batched over blockIdx.z
__global__ void tsplit(const float* __restrict__ W,
                       unsigned short* __restrict__ Wh, unsigned short* __restrict__ Wl,
                       int K, int N)
{
  __shared__ float t[32][33];
  const size_t bo = (size_t)blockIdx.z * K * N;
  const int tx = threadIdx.x, ty = threadIdx.y;
  #pragma unroll
  for (int i = 0; i < 32; i += 8) {
    int kk = blockIdx.y * 32 + ty + i;
    int nn = blockIdx.x * 32 + tx;
    t[ty + i][tx] = W[bo + (size_t)kk * N + nn];
  }
  __syncthreads();
  #pragma unroll
  for (int i = 0; i < 32; i += 8) {
    int nn = blockIdx.x * 32 + ty + i;
    int kk = blockIdx.y * 32 + tx;
    float v = t[tx][ty + i];
    unsigned short hi = f2bf(v);
    Wh[bo + (size_t)nn * K + kk] = hi;
    Wl[bo + (size_t)nn * K + kk] = f2bf(v - bf2f(hi));
  }
}

__global__ void cvt_f16(const float* __restrict__ in, _Float16* __restrict__ o, size_t n)
{
  for (size_t i = (size_t)blockIdx.x * 256 + threadIdx.x; i < n;
       i += (size_t)gridDim.x * 256)
    o[i] = (_Float16)in[i];
}

__global__ void cvt_split(const float* __restrict__ x, unsigned short* __restrict__ xh,
                          unsigned short* __restrict__ xl, size_t n)
{
  size_t i = (size_t)blockIdx.x * 256 + threadIdx.x;
  if (i >= n) return;
  float v = x[i];
  unsigned short hi = f2bf(v);
  xh[i] = hi; xl[i] = f2bf(v - bf2f(hi));
}

// ---------------------------------------------------------------------------
extern "C" void kernel_launch(void* const* d_in, const int* in_sizes, int n_in,
                              void* d_out, int out_size, void* d_ws, size_t ws_size,
                              hipStream_t stream)
{
  (void)in_sizes; (void)n_in; (void)out_size; (void)ws_size;
  const int*   ids = (const int*)  d_in[0];
  const float* emb = (const float*)d_in[1];
  const float* pos = (const float*)d_in[2];
  const float* kw  = (const float*)d_in[3];
  const float* cw  = (const float*)d_in[4];
  const float* cb  = (const float*)d_in[5];
  const float* w1  = (const float*)d_in[6];
  const float* b1  = (const float*)d_in[7];
  const float* w2  = (const float*)d_in[8];
  const float* b2  = (const float*)d_in[9];
  const float* nw  = (const float*)d_in[10];
  const float* pl  = (const float*)d_in[11];
  const float* fnw = (const float*)d_in[12];
  float* out = (float*)d_out;

  constexpr int B = 2, S = 1024, D = 1024, L = 8, V = 32000;
  constexpr int M = B * S;

  // workspace layout (~372 MB)
  size_t off = 0;
  auto alloc = [&](size_t bytes) {
    char* p = (char*)d_ws + off;
    off += (bytes + 255) & ~(size_t)255;
    return (void*)p;
  };
  const size_t WKN = (size_t)L * 2 * D * D;
  unsigned short* kwTh = (unsigned short*)alloc(WKN * 2);
  unsigned short* kwTl = (unsigned short*)alloc(WKN * 2);
  unsigned short* w1Th = (unsigned short*)alloc(WKN * 2);
  unsigned short* w1Tl = (unsigned short*)alloc(WKN * 2);
  unsigned short* w2Th = (unsigned short*)alloc(WKN * 2);
  unsigned short* w2Tl = (unsigned short*)alloc(WKN * 2);
  unsigned short* plTh = (unsigned short*)alloc((size_t)4 * D * D * 2);
  unsigned short* plTl = (unsigned short*)alloc((size_t)4 * D * D * 2);
  _Float16* emb16 = (_Float16*)alloc((size_t)V * D * 2);
  float* x    = (float*)alloc((size_t)M * D * 4);
  unsigned short* xh = (unsigned short*)alloc((size_t)M * D * 2);
  unsigned short* xl = (unsigned short*)alloc((size_t)M * D * 2);
  float* va   = (float*)alloc((size_t)M * 2 * D * 4);
  float* hbuf = (float*)alloc((size_t)M * D * 4);
  unsigned short* zh = (unsigned short*)alloc((size_t)M * D * 2);
  unsigned short* zl = (unsigned short*)alloc((size_t)M * D * 2);
  unsigned short* uh = (unsigned short*)alloc((size_t)M * 2 * D * 2);
  unsigned short* ul = (unsigned short*)alloc((size_t)M * 2 * D * 2);
  float* hfb  = (float*)alloc((size_t)M * D * 4);
  unsigned short* dh = (unsigned short*)alloc((size_t)M * D * 2);
  unsigned short* dl = (unsigned short*)alloc((size_t)M * D * 2);
  _Float16* xf16 = (_Float16*)alloc((size_t)M * D * 2);

  // ---- weight prep: split + transpose to [N,K] bf16, emb -> fp16 ----
  {
    dim3 tb(32, 8);
    tsplit<<<dim3(2 * D / 32, D / 32, L), tb, 0, stream>>>(kw, kwTh, kwTl, D, 2 * D);
    tsplit<<<dim3(2 * D / 32, D / 32, L), tb, 0, stream>>>(w1, w1Th, w1Tl, D, 2 * D);
    tsplit<<<dim3(D / 32, 2 * D / 32, L), tb, 0, stream>>>(w2, w2Th, w2Tl, 2 * D, D);
    tsplit<<<dim3(D / 32, D / 32, 4),     tb, 0, stream>>>(pl, plTh, plTl, D, D);
    cvt_f16<<<4096, 256, 0, stream>>>(emb, emb16, (size_t)V * D);
  }

  embed_norm<<<M, 256, 0, stream>>>(ids, emb, pos, x, xh, xl, S, D);

  for (int i = 0; i < L; ++i) {
    const unsigned short* kh  = kwTh + (size_t)i * 2 * D * D;
    const unsigned short* kl  = kwTl + (size_t)i * 2 * D * D;
    const unsigned short* w1h = w1Th + (size_t)i * 2 * D * D;
    const unsigned short* w1l = w1Tl + (size_t)i * 2 * D * D;
    const unsigned short* w2h = w2Th + (size_t)i * 2 * D * D;
    const unsigned short* w2l = w2Tl + (size_t)i * 2 * D * D;

    // G1: res = x@kw -> epilogue writes v=tanh(theta)*pi (cols<D), a=sigmoid (cols>=D)
    gemm_bt<3, 0, 1><<<dim3(2 * D / 128, M / 128), 256, 0, stream>>>(
        xh, xh, xl, kh, kl, kh, M, 2 * D, D,
        va, nullptr, nullptr, nullptr, nullptr, D);

    scan_kernel<<<B * D / 16, 256, 0, stream>>>(va, hbuf, S, D);

    conv_z<<<(M * D) / 256, 256, 0, stream>>>(
        hbuf, cw + (size_t)i * D * 3, cb + (size_t)i * D, zh, zl, S, D, M * D);

    // G2: u = silu(z@w1 + b1), bf16-split output
    gemm_bt<3, 0, 2><<<dim3(2 * D / 128, M / 128), 256, 0, stream>>>(
        zh, zh, zl, w1h, w1l, w1h, M, 2 * D, D,
        nullptr, uh, ul, b1 + (size_t)i * 2 * D, nullptr, 0);

    // G3: hf = u@w2 + b2
    gemm_bt<3, 0, 3><<<dim3(D / 128, M / 128), 256, 0, stream>>>(
        uh, uh, ul, w2h, w2l, w2h, M, D, 2 * D,
        hfb, nullptr, nullptr, b2 + (size_t)i * D, nullptr, 0);

    const int mode = (i >= L - 4) ? 1 : 0;
    rms_update<<<M, 256, 0, stream>>>(hfb, nw + (size_t)i * D, x,
                                      mode ? dh : xh, mode ? dl : xl, D, mode);
    if (mode) {
      const unsigned short* ph = plTh + (size_t)(i - 4) * D * D;
      const unsigned short* pll = plTl + (size_t)(i - 4) * D * D;
      // G4: x += delta @ plastic
      gemm_bt<3, 0, 4><<<dim3(D / 128, M / 128), 256, 0, stream>>>(
          dh, dh, dl, ph, pll, ph, M, D, D,
          nullptr, nullptr, nullptr, nullptr, x, 0);
      cvt_split<<<(M * D) / 256, 256, 0, stream>>>(x, xh, xl, (size_t)M * D);
    }
  }

  final_norm<<<M, 256, 0, stream>>>(x, fnw, xf16, D);

  // LM head: logits = xf @ emb^T (fp16 MFMA), raw fp32 to d_out
  gemm_bt<1, 1, 0><<<dim3(V / 128, M / 128), 256, 0, stream>>>(
      (const unsigned short*)xf16, nullptr, nullptr,
      (const unsigned short*)emb16, nullptr, nullptr, M, V, D,
      out, nullptr, nullptr, nullptr, nullptr, 0);

  logit_fix<<<M, 256, 0, stream>>>(out, V);
}

// Round 2
// 2868.898 us; speedup vs baseline: 1.2866x; 1.2866x over previous
//
#include <hip/hip_runtime.h>

// ---------------------------------------------------------------------------
// MRT12: 8-layer {keygen GEMM -> tanh/sigmoid -> lerp-scan -> dwconv3 -> MLP
// -> rmsnorm -> residual(+plastic)} -> final norms -> tied LM head -> std fix.
// B=2,S=1024,D=1024,L=8,V=32000. fp32 in/out.
// GEMM v2: m97 structure — global_load_lds width=16 staging, 128x128 tile,
// BK=32, 4 waves. Layer GEMMs do the bf16x2 split (Ah*Bh + Al*Bh + Ah*Bl)
// merged into ONE K-loop (4 LDS buffers, 48 MFMA per k-tile). Head is single
// fp16 with fused per-row sum/sumsq partials for the std fix.
// ---------------------------------------------------------------------------

using short8 = __attribute__((ext_vector_type(8))) short;
using bf16x8 = __attribute__((ext_vector_type(8))) __bf16;
using half8  = __attribute__((ext_vector_type(8))) _Float16;
using f32x4  = __attribute__((ext_vector_type(4))) float;

#define DEVI __device__ __forceinline__

DEVI unsigned short f2bf(float x) {            // RNE float -> bf16 bits
  union { float f; unsigned u; } v; v.f = x;
  unsigned r = v.u + 0x7fffu + ((v.u >> 16) & 1u);
  return (unsigned short)(r >> 16);
}
DEVI float bf2f(unsigned short h) {
  union { float f; unsigned u; } v; v.u = ((unsigned)h) << 16;
  return v.f;
}
DEVI float sigm(float x) { return 1.0f / (1.0f + expf(-x)); }

DEVI float block_sum256(float v) {             // 256-thread block sum
  #pragma unroll
  for (int o = 32; o > 0; o >>= 1) v += __shfl_down(v, o, 64);
  __shared__ float sm[4];
  if ((threadIdx.x & 63) == 0) sm[threadIdx.x >> 6] = v;
  __syncthreads();
  float t = sm[0] + sm[1] + sm[2] + sm[3];
  __syncthreads();
  return t;
}

DEVI void gload16(const void* g, void* l) {    // async global->LDS, 16B/lane
  __builtin_amdgcn_global_load_lds(
      (const __attribute__((address_space(1))) unsigned*)g,
      (__attribute__((address_space(3))) unsigned*)l, 16, 0, 0);
}

// ---------------------------------------------------------------------------
// GEMM v2: C[M,N] = A[M,K] * B[N,K]^T  (+ optional lo-split terms)
// EPI: 0 head (fp32 out + row sum/sumsq partials); 1 keygen (tanh*pi|sigmoid);
//      2 +bias,silu,bf16-split; 3 +bias fp32; 4 xbuf+=C and split(x)
// ---------------------------------------------------------------------------
template<int SPLIT, int FP16, int EPI>
__global__ __launch_bounds__(256) void gemm2(
    const unsigned short* __restrict__ Ah, const unsigned short* __restrict__ Al,
    const unsigned short* __restrict__ Bh, const unsigned short* __restrict__ Bl,
    int M, int N, int K,
    float* __restrict__ outF,
    unsigned short* __restrict__ outH, unsigned short* __restrict__ outL,
    const float* __restrict__ bias, float* __restrict__ xbuf,
    unsigned short* __restrict__ sxh, unsigned short* __restrict__ sxl,
    float* __restrict__ psum, float* __restrict__ psq, int halfN)
{
  constexpr int NB = SPLIT ? 2 : 1;
  __shared__ __align__(16) unsigned short As[NB][128 * 32];
  __shared__ __align__(16) unsigned short Bs[NB][128 * 32];
  const int tid  = threadIdx.x;
  const int lane = tid & 63, wid = tid >> 6;
  const int wr = wid >> 1, wc = wid & 1;

  // XCD-chunked swizzle (nwg % 8 == 0 for all our launches), row-fastest decode
  const int nwg  = gridDim.x;
  const int flat = blockIdx.x;
  const int swz  = (flat & 7) * (nwg >> 3) + (flat >> 3);
  const int MT   = M >> 7;
  const int m0   = (swz % MT) * 128;
  const int nt   = swz / MT;
  const int n0   = nt * 128;

  // staging geometry: lane l of wave w, instr q covers tile row w*32+q*16+(l>>2),
  // cols (l&3)*8..+8 — LDS dest is linear (wave base + lane*16)
  const int srow0 = wid * 32 + (lane >> 2);
  const int scol  = (lane & 3) * 8;

  f32x4 acc[4][4] = {};

  for (int k0 = 0; k0 < K; k0 += 32) {
    __syncthreads();                           // LDS reads of prev tile done
    #pragma unroll
    for (int q = 0; q < 2; ++q) {
      const int row = srow0 + q * 16;
      const size_t ga = (size_t)(m0 + row) * K + k0 + scol;
      const size_t gb = (size_t)(n0 + row) * K + k0 + scol;
      const int lo = wid * 1024 + q * 512;     // ushort offset (wave-uniform)
      gload16(Ah + ga, &As[0][lo]);
      gload16(Bh + gb, &Bs[0][lo]);
      if constexpr (SPLIT) {
        gload16(Al + ga, &As[1][lo]);
        gload16(Bl + gb, &Bs[1][lo]);
      }
    }
    __syncthreads();                           // drains vmcnt -> LDS valid

    const int kq = (lane >> 4) * 8;
    short8 ah_[4], bh_[4], al_[4], bl_[4];
    #pragma unroll
    for (int i = 0; i < 4; ++i) {
      const int ra = (wr * 64 + i * 16 + (lane & 15)) * 32 + kq;
      ah_[i] = *(const short8*)&As[0][ra];
      if constexpr (SPLIT) al_[i] = *(const short8*)&As[1][ra];
    }
    #pragma unroll
    for (int j = 0; j < 4; ++j) {
      const int rb = (wc * 64 + j * 16 + (lane & 15)) * 32 + kq;
      bh_[j] = *(const short8*)&Bs[0][rb];
      if constexpr (SPLIT) bl_[j] = *(const short8*)&Bs[1][rb];
    }
    #pragma unroll
    for (int i = 0; i < 4; ++i)
      #pragma unroll
      for (int j = 0; j < 4; ++j) {
        if constexpr (FP16) {
          acc[i][j] = __builtin_amdgcn_mfma_f32_16x16x32_f16(
              __builtin_bit_cast(half8, ah_[i]), __builtin_bit_cast(half8, bh_[j]),
              acc[i][j], 0, 0, 0);
        } else {
          acc[i][j] = __builtin_amdgcn_mfma_f32_16x16x32_bf16(
              __builtin_bit_cast(bf16x8, ah_[i]), __builtin_bit_cast(bf16x8, bh_[j]),
              acc[i][j], 0, 0, 0);
          if constexpr (SPLIT) {
            acc[i][j] = __builtin_amdgcn_mfma_f32_16x16x32_bf16(
                __builtin_bit_cast(bf16x8, al_[i]), __builtin_bit_cast(bf16x8, bh_[j]),
                acc[i][j], 0, 0, 0);
            acc[i][j] = __builtin_amdgcn_mfma_f32_16x16x32_bf16(
                __builtin_bit_cast(bf16x8, ah_[i]), __builtin_bit_cast(bf16x8, bl_[j]),
                acc[i][j], 0, 0, 0);
          }
        }
      }
  }

  // epilogue: C/D frag: row=(lane>>4)*4+r, col=lane&15 (m89)
  #pragma unroll
  for (int i = 0; i < 4; ++i) {
    const int rbase = m0 + wr * 64 + i * 16 + ((lane >> 4) << 2);
    #pragma unroll
    for (int j = 0; j < 4; ++j) {
      const int col = n0 + wc * 64 + j * 16 + (lane & 15);
      #pragma unroll
      for (int r = 0; r < 4; ++r) {
        float c = acc[i][j][r];
        const size_t idx = (size_t)(rbase + r) * N + col;
        if constexpr (EPI == 0) {
          outF[idx] = c;
        } else if constexpr (EPI == 1) {
          outF[idx] = (col < halfN) ? (tanhf(c) * 3.14159265358979323846f)
                                    : sigm(c);
        } else if constexpr (EPI == 2) {
          c += bias[col];
          float s = c * sigm(c);
          unsigned short hi = f2bf(s);
          outH[idx] = hi; outL[idx] = f2bf(s - bf2f(hi));
        } else if constexpr (EPI == 3) {
          outF[idx] = c + bias[col];
        } else {                                // EPI == 4: x += C, re-split x
          float xn = xbuf[idx] + c;
          xbuf[idx] = xn;
          unsigned short hi = f2bf(xn);
          sxh[idx] = hi; sxl[idx] = f2bf(xn - bf2f(hi));
        }
      }
    }
  }

  // fused per-row sum/sumsq partials for the std fix (head only)
  if constexpr (EPI == 0) {
    const int PW = N >> 6;                      // (N/128)*2 partial cols
    const int pcol = nt * 2 + wc;
    const int myq = lane >> 4, myc = lane & 15;
    #pragma unroll
    for (int i = 0; i < 4; ++i)
      #pragma unroll
      for (int r = 0; r < 4; ++r) {
        float s = 0.f, ss = 0.f;
        #pragma unroll
        for (int j = 0; j < 4; ++j) {
          float v = acc[i][j][r];
          s += v; ss += v * v;
        }
        #pragma unroll
        for (int mk = 1; mk < 16; mk <<= 1) {   // butterfly over the 16 cols
          s  += __shfl_xor(s,  mk, 64);
          ss += __shfl_xor(ss, mk, 64);
        }
        if (myc == i * 4 + r) {
          const int row = m0 + wr * 64 + i * 16 + myq * 4 + r;
          psum[(size_t)row * PW + pcol] = s;
          psq [(size_t)row * PW + pcol] = ss;
        }
      }
  }
}

// ---------------------------------------------------------------------------
// lerp scan: h_t = (1-a_t) h_{t-1} + a_t v_t, per channel (b,d), over s.
// ---------------------------------------------------------------------------
__global__ __launch_bounds__(256) void scan_kernel(
    const float* __restrict__ va, float* __restrict__ h, int S, int D)
{
  const int dl = threadIdx.x & 15;
  const int c  = threadIdx.x >> 4;
  const int ch = blockIdx.x * 16 + dl;
  const int b = ch / D, d = ch % D;
  const float* vb = va + (size_t)b * S * 2 * D + d;
  const float* ab = vb + D;
  const int CH = S / 16;
  float Ar = 1.f, Br = 0.f;
  for (int t = 0; t < CH; ++t) {
    int s = c * CH + t;
    float v = vb[(size_t)s * 2 * D];
    float a = ab[(size_t)s * 2 * D];
    float na = 1.f - a;
    Ar *= na;
    Br = Br * na + a * v;
  }
  __shared__ float Asm[16][16], Bsm[16][16];
  Asm[c][dl] = Ar; Bsm[c][dl] = Br;
  __syncthreads();
  if (c == 0) {
    float run = 0.f;
    for (int cc = 0; cc < 16; ++cc) {
      float A_ = Asm[cc][dl], B_ = Bsm[cc][dl];
      Bsm[cc][dl] = run;
      run = A_ * run + B_;
    }
  }
  __syncthreads();
  float hc = Bsm[c][dl];
  float* hb = h + (size_t)b * S * D + d;
  for (int t = 0; t < CH; ++t) {
    int s = c * CH + t;
    float v = vb[(size_t)s * 2 * D];
    float a = ab[(size_t)s * 2 * D];
    hc = hc + a * (v - hc);
    hb[(size_t)s * D] = hc;
  }
}

__global__ __launch_bounds__(256) void conv_z(
    const float* __restrict__ h, const float* __restrict__ cw,
    const float* __restrict__ cb,
    unsigned short* __restrict__ zh, unsigned short* __restrict__ zl,
    int S, int D, int total)
{
  int idx = blockIdx.x * 256 + threadIdx.x;
  if (idx >= total) return;
  int d = idx % D;
  int s = (idx / D) % S;
  float h0  = h[idx];
  float hm1 = (s >= 1) ? h[idx - D]     : 0.f;
  float hm2 = (s >= 2) ? h[idx - 2 * D] : 0.f;
  float z = h0 + cb[d] + cw[d * 3 + 0] * hm2 + cw[d * 3 + 1] * hm1 + cw[d * 3 + 2] * h0;
  unsigned short hi = f2bf(z);
  zh[idx] = hi; zl[idx] = f2bf(z - bf2f(hi));
}

__global__ __launch_bounds__(256) void rms_update(
    const float* __restrict__ hf, const float* __restrict__ nw,
    float* __restrict__ x,
    unsigned short* __restrict__ oh, unsigned short* __restrict__ ol,
    int D, int mode)
{
  const size_t base = (size_t)blockIdx.x * D;
  float vloc[4]; float ss = 0.f;
  #pragma unroll
  for (int q = 0; q < 4; ++q) {
    float v = hf[base + threadIdx.x + q * 256];
    vloc[q] = v; ss += v * v;
  }
  ss = block_sum256(ss);
  float r = 1.f / sqrtf(ss / D + 1e-8f);
  #pragma unroll
  for (int q = 0; q < 4; ++q) {
    int d = threadIdx.x + q * 256;
    float delta = vloc[q] * r * nw[d];
    float xn = x[base + d] + delta;
    x[base + d] = xn;
    float o = mode ? delta : xn;
    unsigned short hi = f2bf(o);
    oh[base + d] = hi; ol[base + d] = f2bf(o - bf2f(hi));
  }
}

__global__ __launch_bounds__(256) void embed_norm(
    const int* __restrict__ ids, const float* __restrict__ emb,
    const float* __restrict__ pos,
    float* __restrict__ x, unsigned short* __restrict__ xh,
    unsigned short* __restrict__ xl, int S, int D)
{
  const int rowi = blockIdx.x;
  const int s = rowi % S;
  const int tok = ids[rowi];
  const size_t eb = (size_t)tok * D, pb = (size_t)s * D, xb = (size_t)rowi * D;
  float vloc[4]; float ss = 0.f;
  #pragma unroll
  for (int q = 0; q < 4; ++q) {
    int d = threadIdx.x + q * 256;
    float v = emb[eb + d] + pos[pb + d];
    vloc[q] = v; ss += v * v;
  }
  ss = block_sum256(ss);
  float r = 1.f / fmaxf(sqrtf(ss), 1e-12f);
  #pragma unroll
  for (int q = 0; q < 4; ++q) {
    int d = threadIdx.x + q * 256;
    float v = vloc[q] * r;
    x[xb + d] = v;
    unsigned short hi = f2bf(v);
    xh[xb + d] = hi; xl[xb + d] = f2bf(v - bf2f(hi));
  }
}

__global__ __launch_bounds__(256) void final_norm(
    const float* __restrict__ x, const float* __restrict__ w,
    _Float16* __restrict__ xf, int D)
{
  const size_t base = (size_t)blockIdx.x * D;
  float s1 = 0.f, s2 = 0.f;
  float vloc[4], wloc[4];
  #pragma unroll
  for (int q = 0; q < 4; ++q) {
    int d = threadIdx.x + q * 256;
    float v = x[base + d], ww = w[d];
    vloc[q] = v; wloc[q] = ww;
    s1 += v * v; s2 += v * ww * v * ww;
  }
  s1 = block_sum256(s1);
  s2 = block_sum256(s2);
  float r1 = 1.f / sqrtf(s1 / D + 1e-8f);
  float m2 = r1 * r1 * (s2 / D);
  float r2 = 1.f / sqrtf(m2 + 1e-8f);
  float sc = r1 * r2 * 0.8f;
  #pragma unroll
  for (int q = 0; q < 4; ++q) {
    int d = threadIdx.x + q * 256;
    xf[base + d] = (_Float16)(vloc[q] * wloc[q] * sc);
  }
}

// reduce per-row partials -> scale[row] = 1/max(std,1)
__global__ __launch_bounds__(256) void reduce_scale(
    const float* __restrict__ psum, const float* __restrict__ psq,
    float* __restrict__ scale, int PW, int V)
{
  const int row = blockIdx.x;
  float s = 0.f, q = 0.f;
  for (int j = threadIdx.x; j < PW; j += 256) {
    s += psum[(size_t)row * PW + j];
    q += psq [(size_t)row * PW + j];
  }
  s = block_sum256(s);
  q = block_sum256(q);
  float mean = s / V;
  float var = (q - (float)V * mean * mean) / (float)(V - 1);
  var = fmaxf(var, 0.f);
  if (threadIdx.x == 0) scale[row] = 1.f / fmaxf(sqrtf(var), 1.f);
}

// out = clip(out * scale[row], -10, 10), float4 vectorized
__global__ __launch_bounds__(256) void fix_apply(
    float* __restrict__ out, const float* __restrict__ scale, int V)
{
  const int row = blockIdx.y;
  const int j = (blockIdx.x * 256 + threadIdx.x) * 4;
  if (j >= V) return;
  const float sc = scale[row];
  f32x4 v = *(f32x4*)&out[(size_t)row * V + j];
  #pragma unroll
  for (int t = 0; t < 4; ++t)
    v[t] = fminf(fmaxf(v[t] * sc, -10.f), 10.f);
  *(f32x4*)&out[(size_t)row * V + j] = v;
}

// W[K,N] fp32 -> Wh/Wl [N,K] bf16 split (transposed), batched over blockIdx.z
__global__ void tsplit(const float* __restrict__ W,
                       unsigned short* __restrict__ Wh, unsigned short* __restrict__ Wl,
                       int K, int N)
{
  __shared__ float t[32][33];
  const size_t bo = (size_t)blockIdx.z * K * N;
  const int tx = threadIdx.x, ty = threadIdx.y;
  #pragma unroll
  for (int i = 0; i < 32; i += 8) {
    int kk = blockIdx.y * 32 + ty + i;
    int nn = blockIdx.x * 32 + tx;
    t[ty + i][tx] = W[bo + (size_t)kk * N + nn];
  }
  __syncthreads();
  #pragma unroll
  for (int i = 0; i < 32; i += 8) {
    int nn = blockIdx.x * 32 + ty + i;
    int kk = blockIdx.y * 32 + tx;
    float v = t[tx][ty + i];
    unsigned short hi = f2bf(v);
    Wh[bo + (size_t)nn * K + kk] = hi;
    Wl[bo + (size_t)nn * K + kk] = f2bf(v - bf2f(hi));
  }
}

__global__ void cvt_f16(const float* __restrict__ in, _Float16* __restrict__ o, size_t n)
{
  for (size_t i = (size_t)blockIdx.x * 256 + threadIdx.x; i < n;
       i += (size_t)gridDim.x * 256)
    o[i] = (_Float16)in[i];
}

// ---------------------------------------------------------------------------
extern "C" void kernel_launch(void* const* d_in, const int* in_sizes, int n_in,
                              void* d_out, int out_size, void* d_ws, size_t ws_size,
                              hipStream_t stream)
{
  (void)in_sizes; (void)n_in; (void)out_size; (void)ws_size;
  const int*   ids = (const int*)  d_in[0];
  const float* emb = (const float*)d_in[1];
  const float* pos = (const float*)d_in[2];
  const float* kw  = (const float*)d_in[3];
  const float* cw  = (const float*)d_in[4];
  const float* cb  = (const float*)d_in[5];
  const float* w1  = (const float*)d_in[6];
  const float* b1  = (const float*)d_in[7];
  const float* w2  = (const float*)d_in[8];
  const float* b2  = (const float*)d_in[9];
  const float* nw  = (const float*)d_in[10];
  const float* pl  = (const float*)d_in[11];
  const float* fnw = (const float*)d_in[12];
  float* out = (float*)d_out;

  constexpr int B = 2, S = 1024, D = 1024, L = 8, V = 32000;
  constexpr int M = B * S;

  size_t off = 0;
  auto alloc = [&](size_t bytes) {
    char* p = (char*)d_ws + off;
    off += (bytes + 255) & ~(size_t)255;
    return (void*)p;
  };
  const size_t WKN = (size_t)L * 2 * D * D;
  unsigned short* kwTh = (unsigned short*)alloc(WKN * 2);
  unsigned short* kwTl = (unsigned short*)alloc(WKN * 2);
  unsigned short* w1Th = (unsigned short*)alloc(WKN * 2);
  unsigned short* w1Tl = (unsigned short*)alloc(WKN * 2);
  unsigned short* w2Th = (unsigned short*)alloc(WKN * 2);
  unsigned short* w2Tl = (unsigned short*)alloc(WKN * 2);
  unsigned short* plTh = (unsigned short*)alloc((size_t)4 * D * D * 2);
  unsigned short* plTl = (unsigned short*)alloc((size_t)4 * D * D * 2);
  _Float16* emb16 = (_Float16*)alloc((size_t)V * D * 2);
  float* x    = (float*)alloc((size_t)M * D * 4);
  unsigned short* xh = (unsigned short*)alloc((size_t)M * D * 2);
  unsigned short* xl = (unsigned short*)alloc((size_t)M * D * 2);
  float* va   = (float*)alloc((size_t)M * 2 * D * 4);
  float* hbuf = (float*)alloc((size_t)M * D * 4);
  unsigned short* zh = (unsigned short*)alloc((size_t)M * D * 2);
  unsigned short* zl = (unsigned short*)alloc((size_t)M * D * 2);
  unsigned short* uh = (unsigned short*)alloc((size_t)M * 2 * D * 2);
  unsigned short* ul = (unsigned short*)alloc((size_t)M * 2 * D * 2);
  float* hfb  = (float*)alloc((size_t)M * D * 4);
  unsigned short* dh = (unsigned short*)alloc((size_t)M * D * 2);
  unsigned short* dl = (unsigned short*)alloc((size_t)M * D * 2);
  _Float16* xf16 = (_Float16*)alloc((size_t)M * D * 2);

  // head stats buffers overlay va (free at head time): PW = V/64 = 500
  const int PW = V >> 6;
  float* psum  = va;
  float* psq   = va + (size_t)M * PW;
  float* scale = psq + (size_t)M * PW;

  // ---- weight prep ----
  {
    dim3 tb(32, 8);
    tsplit<<<dim3(2 * D / 32, D / 32, L), tb, 0, stream>>>(kw, kwTh, kwTl, D, 2 * D);
    tsplit<<<dim3(2 * D / 32, D / 32, L), tb, 0, stream>>>(w1, w1Th, w1Tl, D, 2 * D);
    tsplit<<<dim3(D / 32, 2 * D / 32, L), tb, 0, stream>>>(w2, w2Th, w2Tl, 2 * D, D);
    tsplit<<<dim3(D / 32, D / 32, 4),     tb, 0, stream>>>(pl, plTh, plTl, D, D);
    cvt_f16<<<4096, 256, 0, stream>>>(emb, emb16, (size_t)V * D);
  }

  embed_norm<<<M, 256, 0, stream>>>(ids, emb, pos, x, xh, xl, S, D);

  for (int i = 0; i < L; ++i) {
    const unsigned short* kh  = kwTh + (size_t)i * 2 * D * D;
    const unsigned short* kl  = kwTl + (size_t)i * 2 * D * D;
    const unsigned short* w1h = w1Th + (size_t)i * 2 * D * D;
    const unsigned short* w1l = w1Tl + (size_t)i * 2 * D * D;
    const unsigned short* w2h = w2Th + (size_t)i * 2 * D * D;
    const unsigned short* w2l = w2Tl + (size_t)i * 2 * D * D;

    // G1: res = x@kw -> v=tanh(theta)*pi | a=sigmoid(alpha)
    gemm2<1, 0, 1><<<(M / 128) * (2 * D / 128), 256, 0, stream>>>(
        xh, xl, kh, kl, M, 2 * D, D,
        va, nullptr, nullptr, nullptr, nullptr, nullptr, nullptr,
        nullptr, nullptr, D);

    scan_kernel<<<B * D / 16, 256, 0, stream>>>(va, hbuf, S, D);

    conv_z<<<(M * D) / 256, 256, 0, stream>>>(
        hbuf, cw + (size_t)i * D * 3, cb + (size_t)i * D, zh, zl, S, D, M * D);

    // G2: u = silu(z@w1 + b1)
    gemm2<1, 0, 2><<<(M / 128) * (2 * D / 128), 256, 0, stream>>>(
        zh, zl, w1h, w1l, M, 2 * D, D,
        nullptr, uh, ul, b1 + (size_t)i * 2 * D, nullptr, nullptr, nullptr,
        nullptr, nullptr, 0);

    // G3: hf = u@w2 + b2
    gemm2<1, 0, 3><<<(M / 128) * (D / 128), 256, 0, stream>>>(
        uh, ul, w2h, w2l, M, D, 2 * D,
        hfb, nullptr, nullptr, b2 + (size_t)i * D, nullptr, nullptr, nullptr,
        nullptr, nullptr, 0);

    const int mode = (i >= L - 4) ? 1 : 0;
    rms_update<<<M, 256, 0, stream>>>(hfb, nw + (size_t)i * D, x,
                                      mode ? dh : xh, mode ? dl : xl, D, mode);
    if (mode) {
      const unsigned short* ph  = plTh + (size_t)(i - 4) * D * D;
      const unsigned short* pll = plTl + (size_t)(i - 4) * D * D;
      // G4: x += delta @ plastic, re-split x in epilogue
      gemm2<1, 0, 4><<<(M / 128) * (D / 128), 256, 0, stream>>>(
          dh, dl, ph, pll, M, D, D,
          nullptr, nullptr, nullptr, nullptr, x, xh, xl,
          nullptr, nullptr, 0);
    }
  }

  final_norm<<<M, 256, 0, stream>>>(x, fnw, xf16, D);

  // LM head: logits = xf @ emb^T (fp16 MFMA) + fused row stats
  gemm2<0, 1, 0><<<(M / 128) * (V / 128), 256, 0, stream>>>(
      (const unsigned short*)xf16, nullptr,
      (const unsigned short*)emb16, nullptr, M, V, D,
      out, nullptr, nullptr, nullptr, nullptr, nullptr, nullptr,
      psum, psq, 0);

  reduce_scale<<<M, 256, 0, stream>>>(psum, psq, scale, PW, V);
  fix_apply<<<dim3((V / 4 + 255) / 256, M), 256, 0, stream>>>(out, scale, V);
}

// Round 3
// 1964.385 us; speedup vs baseline: 1.8790x; 1.4605x over previous
//
#include <hip/hip_runtime.h>

// ---------------------------------------------------------------------------
// MRT12 v3: 2-phase double-buffered GEMMs (T3 minimum recipe), split-K for the
// narrow GEMMs, fused scan+conv. bf16x2-split layer GEMMs, fp16 head.
// B=2,S=1024,D=1024,L=8,V=32000. fp32 in/out.
// ---------------------------------------------------------------------------

using short8 = __attribute__((ext_vector_type(8))) short;
using bf16x8 = __attribute__((ext_vector_type(8))) __bf16;
using half8  = __attribute__((ext_vector_type(8))) _Float16;
using f32x4  = __attribute__((ext_vector_type(4))) float;

#define DEVI __device__ __forceinline__

DEVI unsigned short f2bf(float x) {            // RNE float -> bf16 bits
  union { float f; unsigned u; } v; v.f = x;
  unsigned r = v.u + 0x7fffu + ((v.u >> 16) & 1u);
  return (unsigned short)(r >> 16);
}
DEVI float bf2f(unsigned short h) {
  union { float f; unsigned u; } v; v.u = ((unsigned)h) << 16;
  return v.f;
}
DEVI float sigm(float x) { return 1.0f / (1.0f + expf(-x)); }

DEVI float block_sum256(float v) {
  #pragma unroll
  for (int o = 32; o > 0; o >>= 1) v += __shfl_down(v, o, 64);
  __shared__ float sm[4];
  if ((threadIdx.x & 63) == 0) sm[threadIdx.x >> 6] = v;
  __syncthreads();
  float t = sm[0] + sm[1] + sm[2] + sm[3];
  __syncthreads();
  return t;
}

DEVI void gload16(const void* g, void* l) {    // async global->LDS, 16B/lane
  __builtin_amdgcn_global_load_lds(
      (const __attribute__((address_space(1))) unsigned*)g,
      (__attribute__((address_space(3))) unsigned*)l, 16, 0, 0);
}

// ---------------------------------------------------------------------------
// GEMM v3: C[M,N] = A[M,K] * B[N,K]^T (+ split lo terms). 128x128 tile, BK=32,
// 4 waves, 2-phase double-buffered LDS via global_load_lds width=16.
// EPI: 0 head (fp32 C + fused row sum/sumsq partials)
//      1 keygen -> vaT[2D][M] channel-major, tanh*pi | sigmoid
//      2 +bias, silu, bf16-split out [M][N]
//      5 raw fp32 partial at outF + ks*M*N (split-K)
// ---------------------------------------------------------------------------
template<int SPLIT, int FP16, int EPI, int KSPLIT>
__global__ __launch_bounds__(256) void gemm3(
    const unsigned short* __restrict__ Ah, const unsigned short* __restrict__ Al,
    const unsigned short* __restrict__ Bh, const unsigned short* __restrict__ Bl,
    int M, int N, int K,
    float* __restrict__ outF,
    unsigned short* __restrict__ outH, unsigned short* __restrict__ outL,
    const float* __restrict__ bias,
    float* __restrict__ psum, float* __restrict__ psq, int halfN)
{
  constexpr int NARR = SPLIT ? 4 : 2;            // Ah,Bh[,Al,Bl]
  __shared__ __align__(16) unsigned short lds[2][NARR][128 * 32];
  const int tid  = threadIdx.x;
  const int lane = tid & 63, wid = tid >> 6;
  const int wr = wid >> 1, wc = wid & 1;

  // XCD-chunked swizzle (nwg % 8 == 0 always here), m-fastest decode
  const int nwg  = gridDim.x;
  const int flat = blockIdx.x;
  const int swz  = (flat & 7) * (nwg >> 3) + (flat >> 3);
  const int ks   = (KSPLIT > 1) ? (swz % KSPLIT) : 0;
  const int tile = (KSPLIT > 1) ? (swz / KSPLIT) : swz;
  const int MT   = M >> 7;
  const int m0   = (tile % MT) * 128;
  const int nt   = tile / MT;
  const int n0   = nt * 128;
  const int Kc   = K / KSPLIT;
  const int kbase = ks * Kc;
  const int NT   = Kc / 32;

  const int srow0 = wid * 32 + (lane >> 2);      // staging row
  const int scol  = (lane & 3) * 8;              // staging col (elements)

  auto stage = [&](int b, int k0) {
    #pragma unroll
    for (int q = 0; q < 2; ++q) {
      const int row = srow0 + q * 16;
      const size_t ga = (size_t)(m0 + row) * K + k0 + scol;
      const size_t gb = (size_t)(n0 + row) * K + k0 + scol;
      const int lo = wid * 1024 + q * 512;       // ushort offset, wave-uniform
      gload16(Ah + ga, &lds[b][0][lo]);
      gload16(Bh + gb, &lds[b][1][lo]);
      if constexpr (SPLIT) {
        gload16(Al + ga, &lds[b][2][lo]);
        gload16(Bl + gb, &lds[b][3][lo]);
      }
    }
  };

  f32x4 acc[4][4] = {};

  stage(0, kbase);
  __syncthreads();                               // drain vmcnt -> buf0 ready
  int cur = 0;
  for (int t = 0; t < NT; ++t) {
    if (t + 1 < NT) stage(cur ^ 1, kbase + (t + 1) * 32);  // prefetch next
    const int kq = (lane >> 4) * 8;
    short8 ah_[4], bh_[4], al_[4], bl_[4];
    #pragma unroll
    for (int i = 0; i < 4; ++i) {
      const int ra = (wr * 64 + i * 16 + (lane & 15)) * 32 + kq;
      ah_[i] = *(const short8*)&lds[cur][0][ra];
      if constexpr (SPLIT) al_[i] = *(const short8*)&lds[cur][2][ra];
    }
    #pragma unroll
    for (int j = 0; j < 4; ++j) {
      const int rb = (wc * 64 + j * 16 + (lane & 15)) * 32 + kq;
      bh_[j] = *(const short8*)&lds[cur][1][rb];
      if constexpr (SPLIT) bl_[j] = *(const short8*)&lds[cur][3][rb];
    }
    #pragma unroll
    for (int i = 0; i < 4; ++i)
      #pragma unroll
      for (int j = 0; j < 4; ++j) {
        if constexpr (FP16) {
          acc[i][j] = __builtin_amdgcn_mfma_f32_16x16x32_f16(
              __builtin_bit_cast(half8, ah_[i]), __builtin_bit_cast(half8, bh_[j]),
              acc[i][j], 0, 0, 0);
        } else {
          acc[i][j] = __builtin_amdgcn_mfma_f32_16x16x32_bf16(
              __builtin_bit_cast(bf16x8, ah_[i]), __builtin_bit_cast(bf16x8, bh_[j]),
              acc[i][j], 0, 0, 0);
          if constexpr (SPLIT) {
            acc[i][j] = __builtin_amdgcn_mfma_f32_16x16x32_bf16(
                __builtin_bit_cast(bf16x8, al_[i]), __builtin_bit_cast(bf16x8, bh_[j]),
                acc[i][j], 0, 0, 0);
            acc[i][j] = __builtin_amdgcn_mfma_f32_16x16x32_bf16(
                __builtin_bit_cast(bf16x8, ah_[i]), __builtin_bit_cast(bf16x8, bl_[j]),
                acc[i][j], 0, 0, 0);
          }
        }
      }
    __syncthreads();       // all reads of cur done + prefetch loads drained
    cur ^= 1;
  }

  // epilogue: C/D frag row=(lane>>4)*4+r, col=lane&15 (m89)
  const size_t MN = (size_t)M * N;
  #pragma unroll
  for (int i = 0; i < 4; ++i) {
    const int rbase = m0 + wr * 64 + i * 16 + ((lane >> 4) << 2);
    #pragma unroll
    for (int j = 0; j < 4; ++j) {
      const int col = n0 + wc * 64 + j * 16 + (lane & 15);
      if constexpr (EPI == 1) {                  // channel-major vaT[col][row]
        f32x4 v;
        #pragma unroll
        for (int r = 0; r < 4; ++r) {
          float c = acc[i][j][r];
          v[r] = (col < halfN) ? (tanhf(c) * 3.14159265358979323846f) : sigm(c);
        }
        *(f32x4*)&outF[(size_t)col * M + rbase] = v;
      } else {
        #pragma unroll
        for (int r = 0; r < 4; ++r) {
          float c = acc[i][j][r];
          const size_t idx = (size_t)(rbase + r) * N + col;
          if constexpr (EPI == 0) {
            outF[idx] = c;
          } else if constexpr (EPI == 2) {
            c += bias[col];
            float s = c * sigm(c);
            unsigned short hi = f2bf(s);
            outH[idx] = hi; outL[idx] = f2bf(s - bf2f(hi));
          } else if constexpr (EPI == 5) {
            outF[(size_t)ks * MN + idx] = c;
          }
        }
      }
    }
  }

  if constexpr (EPI == 0) {                      // fused row stats (head)
    const int PW = N >> 6;
    const int pcol = nt * 2 + wc;
    const int myq = lane >> 4, myc = lane & 15;
    #pragma unroll
    for (int i = 0; i < 4; ++i)
      #pragma unroll
      for (int r = 0; r < 4; ++r) {
        float s = 0.f, ss = 0.f;
        #pragma unroll
        for (int j = 0; j < 4; ++j) {
          float v = acc[i][j][r];
          s += v; ss += v * v;
        }
        #pragma unroll
        for (int mk = 1; mk < 16; mk <<= 1) {
          s  += __shfl_xor(s,  mk, 64);
          ss += __shfl_xor(ss, mk, 64);
        }
        if (myc == i * 4 + r) {
          const int row = m0 + wr * 64 + i * 16 + myq * 4 + r;
          psum[(size_t)row * PW + pcol] = s;
          psq [(size_t)row * PW + pcol] = ss;
        }
      }
  }
}

// ---------------------------------------------------------------------------
// Fused lerp-scan + causal dwconv3: reads vaT[2D][M] channel-major, emits
// z = h + (conv(h)+cb) as bf16 split [M][D]. 16 channels x 16 chunks (CH=64).
// Chunk-boundary h_{s0-1}, h_{s0-2} from per-chunk affine compositions.
// ---------------------------------------------------------------------------
__global__ __launch_bounds__(256) void scanconv(
    const float* __restrict__ vaT, const float* __restrict__ cw,
    const float* __restrict__ cb,
    unsigned short* __restrict__ zh, unsigned short* __restrict__ zl,
    int S, int D, int M)
{
  const int dl = threadIdx.x & 15;               // channel in block
  const int c  = threadIdx.x >> 4;               // chunk 0..15
  const int ch = blockIdx.x * 16 + dl;
  const int b = ch >> 10, d = ch & 1023;
  const int CH = S / 16;                         // 64
  const float* vrow = vaT + (size_t)d * M + b * S;
  const float* arow = vaT + (size_t)(D + d) * M + b * S;
  const int s0 = c * CH;

  // pass 1: full-chunk (A,B) and first-(CH-1) (A',B')
  float A = 1.f, Bv = 0.f, Apm = 1.f, Bpm = 0.f;
  for (int t = 0; t < CH; t += 4) {
    f32x4 v4 = *(const f32x4*)&vrow[s0 + t];
    f32x4 a4 = *(const f32x4*)&arow[s0 + t];
    #pragma unroll
    for (int r = 0; r < 4; ++r) {
      if (t + r == CH - 1) { Apm = A; Bpm = Bv; }
      float na = 1.f - a4[r];
      A *= na;
      Bv = Bv * na + a4[r] * v4[r];
    }
  }
  __shared__ float Asm[16][17], Bsm[16][17], Aps[16][17], Bps[16][17];
  Asm[c][dl] = A; Bsm[c][dl] = Bv; Aps[c][dl] = Apm; Bps[c][dl] = Bpm;
  __syncthreads();
  if (c == 0) {                                  // serial exclusive prefix
    float run = 0.f;
    for (int cc = 0; cc < 16; ++cc) {
      float A_ = Asm[cc][dl], B_ = Bsm[cc][dl];
      Bsm[cc][dl] = run;                         // h_in(cc) = h_{s0-1}
      run = A_ * run + B_;
    }
  }
  __syncthreads();
  float hm1 = Bsm[c][dl];
  float hm2 = (c == 0) ? 0.f
            : (Aps[c - 1][dl] * Bsm[c - 1][dl] + Bps[c - 1][dl]);

  // pass 2: recurrence + conv + bf16-split store
  const float w0 = cw[d * 3 + 0], w1 = cw[d * 3 + 1], w2 = cw[d * 3 + 2];
  const float bc = cb[d];
  for (int t = 0; t < CH; t += 4) {
    f32x4 v4 = *(const f32x4*)&vrow[s0 + t];
    f32x4 a4 = *(const f32x4*)&arow[s0 + t];
    #pragma unroll
    for (int r = 0; r < 4; ++r) {
      float h = hm1 + a4[r] * (v4[r] - hm1);
      float z = h + bc + w0 * hm2 + w1 * hm1 + w2 * h;
      const size_t oi = (size_t)(b * S + s0 + t + r) * D + d;
      unsigned short hi = f2bf(z);
      zh[oi] = hi; zl[oi] = f2bf(z - bf2f(hi));
      hm2 = hm1; hm1 = h;
    }
  }
}

// v = p0+p1+bias; delta = rmsnorm(v)*nw; x += delta; split(mode?delta:x_new)
__global__ __launch_bounds__(256) void rms_fuse(
    const float* __restrict__ p, const float* __restrict__ bias,
    const float* __restrict__ nw, float* __restrict__ x,
    unsigned short* __restrict__ oh, unsigned short* __restrict__ ol,
    int D, int mode, size_t MN)
{
  const size_t base = (size_t)blockIdx.x * D;
  float vloc[4]; float ss = 0.f;
  #pragma unroll
  for (int q = 0; q < 4; ++q) {
    int d = threadIdx.x + q * 256;
    float v = p[base + d] + p[MN + base + d] + bias[d];
    vloc[q] = v; ss += v * v;
  }
  ss = block_sum256(ss);
  float r = 1.f / sqrtf(ss / D + 1e-8f);
  #pragma unroll
  for (int q = 0; q < 4; ++q) {
    int d = threadIdx.x + q * 256;
    float delta = vloc[q] * r * nw[d];
    float xn = x[base + d] + delta;
    x[base + d] = xn;
    float o = mode ? delta : xn;
    unsigned short hi = f2bf(o);
    oh[base + d] = hi; ol[base + d] = f2bf(o - bf2f(hi));
  }
}

// x += p0+p1 (split-K partials of delta@plastic); re-split x
__global__ __launch_bounds__(256) void xupd(
    const float* __restrict__ p, float* __restrict__ x,
    unsigned short* __restrict__ xh, unsigned short* __restrict__ xl, size_t MN)
{
  size_t i = (size_t)blockIdx.x * 256 + threadIdx.x;
  if (i >= MN) return;
  float xn = x[i] + p[i] + p[MN + i];
  x[i] = xn;
  unsigned short hi = f2bf(xn);
  xh[i] = hi; xl[i] = f2bf(xn - bf2f(hi));
}

__global__ __launch_bounds__(256) void embed_norm(
    const int* __restrict__ ids, const float* __restrict__ emb,
    const float* __restrict__ pos,
    float* __restrict__ x, unsigned short* __restrict__ xh,
    unsigned short* __restrict__ xl, int S, int D)
{
  const int rowi = blockIdx.x;
  const int s = rowi % S;
  const int tok = ids[rowi];
  const size_t eb = (size_t)tok * D, pb = (size_t)s * D, xb = (size_t)rowi * D;
  float vloc[4]; float ss = 0.f;
  #pragma unroll
  for (int q = 0; q < 4; ++q) {
    int d = threadIdx.x + q * 256;
    float v = emb[eb + d] + pos[pb + d];
    vloc[q] = v; ss += v * v;
  }
  ss = block_sum256(ss);
  float r = 1.f / fmaxf(sqrtf(ss), 1e-12f);
  #pragma unroll
  for (int q = 0; q < 4; ++q) {
    int d = threadIdx.x + q * 256;
    float v = vloc[q] * r;
    x[xb + d] = v;
    unsigned short hi = f2bf(v);
    xh[xb + d] = hi; xl[xb + d] = f2bf(v - bf2f(hi));
  }
}

__global__ __launch_bounds__(256) void final_norm(
    const float* __restrict__ x, const float* __restrict__ w,
    _Float16* __restrict__ xf, int D)
{
  const size_t base = (size_t)blockIdx.x * D;
  float s1 = 0.f, s2 = 0.f;
  float vloc[4], wloc[4];
  #pragma unroll
  for (int q = 0; q < 4; ++q) {
    int d = threadIdx.x + q * 256;
    float v = x[base + d], ww = w[d];
    vloc[q] = v; wloc[q] = ww;
    s1 += v * v; s2 += v * ww * v * ww;
  }
  s1 = block_sum256(s1);
  s2 = block_sum256(s2);
  float r1 = 1.f / sqrtf(s1 / D + 1e-8f);
  float m2 = r1 * r1 * (s2 / D);
  float r2 = 1.f / sqrtf(m2 + 1e-8f);
  float sc = r1 * r2 * 0.8f;
  #pragma unroll
  for (int q = 0; q < 4; ++q) {
    int d = threadIdx.x + q * 256;
    xf[base + d] = (_Float16)(vloc[q] * wloc[q] * sc);
  }
}

__global__ __launch_bounds__(256) void reduce_scale(
    const float* __restrict__ psum, const float* __restrict__ psq,
    float* __restrict__ scale, int PW, int V)
{
  const int row = blockIdx.x;
  float s = 0.f, q = 0.f;
  for (int j = threadIdx.x; j < PW; j += 256) {
    s += psum[(size_t)row * PW + j];
    q += psq [(size_t)row * PW + j];
  }
  s = block_sum256(s);
  q = block_sum256(q);
  float mean = s / V;
  float var = (q - (float)V * mean * mean) / (float)(V - 1);
  var = fmaxf(var, 0.f);
  if (threadIdx.x == 0) scale[row] = 1.f / fmaxf(sqrtf(var), 1.f);
}

__global__ __launch_bounds__(256) void fix_apply(
    float* __restrict__ out, const float* __restrict__ scale, int V)
{
  const int row = blockIdx.y;
  const int j = (blockIdx.x * 256 + threadIdx.x) * 4;
  if (j >= V) return;
  const float sc = scale[row];
  f32x4 v = *(f32x4*)&out[(size_t)row * V + j];
  #pragma unroll
  for (int t = 0; t < 4; ++t)
    v[t] = fminf(fmaxf(v[t] * sc, -10.f), 10.f);
  *(f32x4*)&out[(size_t)row * V + j] = v;
}

// W[K,N] fp32 -> Wh/Wl [N,K] bf16 split (transposed), batched over blockIdx.z
__global__ void tsplit(const float* __restrict__ W,
                       unsigned short* __restrict__ Wh, unsigned short* __restrict__ Wl,
                       int K, int N)
{
  __shared__ float t[32][33];
  const size_t bo = (size_t)blockIdx.z * K * N;
  const int tx = threadIdx.x, ty = threadIdx.y;
  #pragma unroll
  for (int i = 0; i < 32; i += 8) {
    int kk = blockIdx.y * 32 + ty + i;
    int nn = blockIdx.x * 32 + tx;
    t[ty + i][tx] = W[bo + (size_t)kk * N + nn];
  }
  __syncthreads();
  #pragma unroll
  for (int i = 0; i < 32; i += 8) {
    int nn = blockIdx.x * 32 + ty + i;
    int kk = blockIdx.y * 32 + tx;
    float v = t[tx][ty + i];
    unsigned short hi = f2bf(v);
    Wh[bo + (size_t)nn * K + kk] = hi;
    Wl[bo + (size_t)nn * K + kk] = f2bf(v - bf2f(hi));
  }
}

__global__ void cvt_f16(const float* __restrict__ in, _Float16* __restrict__ o, size_t n)
{
  for (size_t i = (size_t)blockIdx.x * 256 + threadIdx.x; i < n;
       i += (size_t)gridDim.x * 256)
    o[i] = (_Float16)in[i];
}

// ---------------------------------------------------------------------------
extern "C" void kernel_launch(void* const* d_in, const int* in_sizes, int n_in,
                              void* d_out, int out_size, void* d_ws, size_t ws_size,
                              hipStream_t stream)
{
  (void)in_sizes; (void)n_in; (void)out_size; (void)ws_size;
  const int*   ids = (const int*)  d_in[0];
  const float* emb = (const float*)d_in[1];
  const float* pos = (const float*)d_in[2];
  const float* kw  = (const float*)d_in[3];
  const float* cw  = (const float*)d_in[4];
  const float* cb  = (const float*)d_in[5];
  const float* w1  = (const float*)d_in[6];
  const float* b1  = (const float*)d_in[7];
  const float* w2  = (const float*)d_in[8];
  const float* b2  = (const float*)d_in[9];
  const float* nw  = (const float*)d_in[10];
  const float* pl  = (const float*)d_in[11];
  const float* fnw = (const float*)d_in[12];
  float* out = (float*)d_out;

  constexpr int B = 2, S = 1024, D = 1024, L = 8, V = 32000;
  constexpr int M = B * S;
  const size_t MN = (size_t)M * D;

  size_t off = 0;
  auto alloc = [&](size_t bytes) {
    char* p = (char*)d_ws + off;
    off += (bytes + 255) & ~(size_t)255;
    return (void*)p;
  };
  const size_t WKN = (size_t)L * 2 * D * D;
  unsigned short* kwTh = (unsigned short*)alloc(WKN * 2);
  unsigned short* kwTl = (unsigned short*)alloc(WKN * 2);
  unsigned short* w1Th = (unsigned short*)alloc(WKN * 2);
  unsigned short* w1Tl = (unsigned short*)alloc(WKN * 2);
  unsigned short* w2Th = (unsigned short*)alloc(WKN * 2);
  unsigned short* w2Tl = (unsigned short*)alloc(WKN * 2);
  unsigned short* plTh = (unsigned short*)alloc((size_t)4 * D * D * 2);
  unsigned short* plTl = (unsigned short*)alloc((size_t)4 * D * D * 2);
  _Float16* emb16 = (_Float16*)alloc((size_t)V * D * 2);
  float* x    = (float*)alloc(MN * 4);
  unsigned short* xh = (unsigned short*)alloc(MN * 2);
  unsigned short* xl = (unsigned short*)alloc(MN * 2);
  float* vaT  = (float*)alloc((size_t)M * 2 * D * 4);   // [2D][M]
  float* pbuf = (float*)alloc(2 * MN * 4);              // split-K partials
  unsigned short* zh = (unsigned short*)alloc(MN * 2);
  unsigned short* zl = (unsigned short*)alloc(MN * 2);
  unsigned short* uh = (unsigned short*)alloc((size_t)M * 2 * D * 2);
  unsigned short* ul = (unsigned short*)alloc((size_t)M * 2 * D * 2);
  unsigned short* dh  = (unsigned short*)alloc(MN * 2);
  unsigned short* dlo = (unsigned short*)alloc(MN * 2);
  _Float16* xf16 = (_Float16*)alloc(MN * 2);

  // head stats overlay vaT (free at head time): PW = V/64 = 500
  const int PW = V >> 6;
  float* psum  = vaT;
  float* psq   = vaT + (size_t)M * PW;
  float* scale = psq + (size_t)M * PW;

  // ---- weight prep ----
  {
    dim3 tb(32, 8);
    tsplit<<<dim3(2 * D / 32, D / 32, L), tb, 0, stream>>>(kw, kwTh, kwTl, D, 2 * D);
    tsplit<<<dim3(2 * D / 32, D / 32, L), tb, 0, stream>>>(w1, w1Th, w1Tl, D, 2 * D);
    tsplit<<<dim3(D / 32, 2 * D / 32, L), tb, 0, stream>>>(w2, w2Th, w2Tl, 2 * D, D);
    tsplit<<<dim3(D / 32, D / 32, 4),     tb, 0, stream>>>(pl, plTh, plTl, D, D);
    cvt_f16<<<4096, 256, 0, stream>>>(emb, emb16, (size_t)V * D);
  }

  embed_norm<<<M, 256, 0, stream>>>(ids, emb, pos, x, xh, xl, S, D);

  for (int i = 0; i < L; ++i) {
    const unsigned short* kh  = kwTh + (size_t)i * 2 * D * D;
    const unsigned short* kl  = kwTl + (size_t)i * 2 * D * D;
    const unsigned short* w1h = w1Th + (size_t)i * 2 * D * D;
    const unsigned short* w1l = w1Tl + (size_t)i * 2 * D * D;
    const unsigned short* w2h = w2Th + (size_t)i * 2 * D * D;
    const unsigned short* w2l = w2Tl + (size_t)i * 2 * D * D;

    // G1: res = x@kw -> vaT channel-major, v=tanh*pi | a=sigmoid
    gemm3<1, 0, 1, 1><<<(M / 128) * (2 * D / 128), 256, 0, stream>>>(
        xh, xl, kh, kl, M, 2 * D, D,
        vaT, nullptr, nullptr, nullptr, nullptr, nullptr, D);

    // fused scan + conv -> zh/zl
    scanconv<<<B * D / 16, 256, 0, stream>>>(
        vaT, cw + (size_t)i * D * 3, cb + (size_t)i * D, zh, zl, S, D, M);

    // G2: u = silu(z@w1 + b1)
    gemm3<1, 0, 2, 1><<<(M / 128) * (2 * D / 128), 256, 0, stream>>>(
        zh, zl, w1h, w1l, M, 2 * D, D,
        nullptr, uh, ul, b1 + (size_t)i * 2 * D, nullptr, nullptr, 0);

    // G3: hf partials = u@w2 (split-K x2)
    gemm3<1, 0, 5, 2><<<(M / 128) * (D / 128) * 2, 256, 0, stream>>>(
        uh, ul, w2h, w2l, M, D, 2 * D,
        pbuf, nullptr, nullptr, nullptr, nullptr, nullptr, 0);

    const int mode = (i >= L - 4) ? 1 : 0;
    rms_fuse<<<M, 256, 0, stream>>>(pbuf, b2 + (size_t)i * D, nw + (size_t)i * D,
                                    x, mode ? dh : xh, mode ? dlo : xl,
                                    D, mode, MN);
    if (mode) {
      const unsigned short* ph  = plTh + (size_t)(i - 4) * D * D;
      const unsigned short* pll = plTl + (size_t)(i - 4) * D * D;
      // G4: partials = delta @ plastic (split-K x2)
      gemm3<1, 0, 5, 2><<<(M / 128) * (D / 128) * 2, 256, 0, stream>>>(
          dh, dlo, ph, pll, M, D, D,
          pbuf, nullptr, nullptr, nullptr, nullptr, nullptr, 0);
      xupd<<<(int)(MN / 256), 256, 0, stream>>>(pbuf, x, xh, xl, MN);
    }
  }

  final_norm<<<M, 256, 0, stream>>>(x, fnw, xf16, D);

  // LM head: logits = xf @ emb^T (fp16 MFMA) + fused row stats
  gemm3<0, 1, 0, 1><<<(M / 128) * (V / 128), 256, 0, stream>>>(
      (const unsigned short*)xf16, nullptr,
      (const unsigned short*)emb16, nullptr, M, V, D,
      out, nullptr, nullptr, nullptr, psum, psq, 0);

  reduce_scale<<<M, 256, 0, stream>>>(psum, psq, scale, PW, V);
  fix_apply<<<dim3((V / 4 + 255) / 256, M), 256, 0, stream>>>(out, scale, V);
}

// Round 4
// 1348.186 us; speedup vs baseline: 2.7378x; 1.4571x over previous
//
#include <hip/hip_runtime.h>

// ---------------------------------------------------------------------------
// MRT12 v4: fp16-single GEMMs, BK=64 tiles with XOR bank-swizzle
// (slot ^= row&7, pre-swizzled global source + swizzled ds_read), 2-phase
// double-buffer via global_load_lds width=16. Fused scan+conv.
// B=2,S=1024,D=1024,L=8,V=32000. fp32 in/out.
// ---------------------------------------------------------------------------

using short8 = __attribute__((ext_vector_type(8))) short;
using half8  = __attribute__((ext_vector_type(8))) _Float16;
using f32x4  = __attribute__((ext_vector_type(4))) float;

#define DEVI __device__ __forceinline__

DEVI float sigm(float x) { return 1.0f / (1.0f + expf(-x)); }

DEVI float block_sum256(float v) {
  #pragma unroll
  for (int o = 32; o > 0; o >>= 1) v += __shfl_down(v, o, 64);
  __shared__ float sm[4];
  if ((threadIdx.x & 63) == 0) sm[threadIdx.x >> 6] = v;
  __syncthreads();
  float t = sm[0] + sm[1] + sm[2] + sm[3];
  __syncthreads();
  return t;
}

DEVI void gload16(const void* g, void* l) {    // async global->LDS, 16B/lane
  __builtin_amdgcn_global_load_lds(
      (const __attribute__((address_space(1))) unsigned*)g,
      (__attribute__((address_space(3))) unsigned*)l, 16, 0, 0);
}

// ---------------------------------------------------------------------------
// GEMM v4: C[M,N] = A[M,K] * B[N,K]^T, fp16 MFMA. 128x128 tile, BK=64,
// 4 waves, 2-phase dbuf. LDS rows are 128B; 16B slot index XOR'd with row&7
// on BOTH the global source (staging) and the ds_read -> 2-way (free) banks.
// EPI: 0 head (fp32 C + fused row stats); 1 keygen -> vaT[2D][M], tanh|sigm;
//      2 +bias, silu, fp16 out; 5 raw fp32 partial at outF + ks*M*N
// ---------------------------------------------------------------------------
template<int EPI, int KSPLIT>
__global__ __launch_bounds__(256) void gemm4(
    const _Float16* __restrict__ A, const _Float16* __restrict__ B,
    int M, int N, int K,
    float* __restrict__ outF, _Float16* __restrict__ outH,
    const float* __restrict__ bias,
    float* __restrict__ psum, float* __restrict__ psq, int halfN)
{
  __shared__ __align__(16) unsigned short lds[2][2][128 * 64];
  const int tid  = threadIdx.x;
  const int lane = tid & 63, wid = tid >> 6;
  const int wr = wid >> 1, wc = wid & 1;

  // XCD-chunked swizzle (nwg % 8 == 0 for all launches), m-fastest decode
  const int nwg  = gridDim.x;
  const int flat = blockIdx.x;
  const int swz  = (flat & 7) * (nwg >> 3) + (flat >> 3);
  const int ks   = (KSPLIT > 1) ? (swz % KSPLIT) : 0;
  const int tile = (KSPLIT > 1) ? (swz / KSPLIT) : swz;
  const int MT   = M >> 7;
  const int m0   = (tile % MT) * 128;
  const int nt   = tile / MT;
  const int n0   = nt * 128;
  const int Kc   = K / KSPLIT;
  const int kbase = ks * Kc;
  const int NT   = Kc / 64;

  const int lq = lane & 7;              // 16B slot within 128B row
  const int lr = lane >> 3;             // row within 8-row group

  auto stage = [&](int b, int k0) {
    #pragma unroll
    for (int q = 0; q < 4; ++q) {
      const int row = wid * 32 + q * 8 + lr;
      const int colel = (lq ^ (row & 7)) << 3;     // pre-swizzled source slot
      const size_t ga = (size_t)(m0 + row) * K + k0 + colel;
      const size_t gb = (size_t)(n0 + row) * K + k0 + colel;
      const int lo = wid * 2048 + q * 512;         // ushort offset, wave-uniform
      gload16(A + ga, &lds[b][0][lo]);
      gload16(B + gb, &lds[b][1][lo]);
    }
  };

  f32x4 acc[4][4] = {};
  const int myr = lane & 15;
  const int kq  = lane >> 4;            // k-quad 0..3

  stage(0, kbase);
  __syncthreads();
  int cur = 0;
  for (int t = 0; t < NT; ++t) {
    if (t + 1 < NT) stage(cur ^ 1, kbase + (t + 1) * 64);
    #pragma unroll
    for (int kk = 0; kk < 2; ++kk) {
      const int s = kk * 4 + kq;
      short8 af[4], bfr[4];
      #pragma unroll
      for (int i = 0; i < 4; ++i) {
        const int ra = wr * 64 + i * 16 + myr;
        af[i] = *(const short8*)&lds[cur][0][ra * 64 + ((s ^ (ra & 7)) << 3)];
        const int rb = wc * 64 + i * 16 + myr;
        bfr[i] = *(const short8*)&lds[cur][1][rb * 64 + ((s ^ (rb & 7)) << 3)];
      }
      #pragma unroll
      for (int i = 0; i < 4; ++i)
        #pragma unroll
        for (int j = 0; j < 4; ++j)
          acc[i][j] = __builtin_amdgcn_mfma_f32_16x16x32_f16(
              __builtin_bit_cast(half8, af[i]), __builtin_bit_cast(half8, bfr[j]),
              acc[i][j], 0, 0, 0);
    }
    __syncthreads();                    // reads done + prefetch drained
    cur ^= 1;
  }

  // epilogue: C/D frag row=(lane>>4)*4+r, col=lane&15 (m89)
  const size_t MN = (size_t)M * N;
  #pragma unroll
  for (int i = 0; i < 4; ++i) {
    const int rbase = m0 + wr * 64 + i * 16 + (kq << 2);
    #pragma unroll
    for (int j = 0; j < 4; ++j) {
      const int col = n0 + wc * 64 + j * 16 + myr;
      if constexpr (EPI == 1) {                    // channel-major vaT[col][row]
        f32x4 v;
        #pragma unroll
        for (int r = 0; r < 4; ++r) {
          float c = acc[i][j][r];
          v[r] = (col < halfN) ? (tanhf(c) * 3.14159265358979323846f) : sigm(c);
        }
        *(f32x4*)&outF[(size_t)col * M + rbase] = v;
      } else {
        #pragma unroll
        for (int r = 0; r < 4; ++r) {
          float c = acc[i][j][r];
          const size_t idx = (size_t)(rbase + r) * N + col;
          if constexpr (EPI == 0) {
            outF[idx] = c;
          } else if constexpr (EPI == 2) {
            c += bias[col];
            outH[idx] = (_Float16)(c * sigm(c));   // silu
          } else if constexpr (EPI == 5) {
            outF[(size_t)ks * MN + idx] = c;
          }
        }
      }
    }
  }

  if constexpr (EPI == 0) {                        // fused row stats (head)
    const int PW = N >> 6;
    const int pcol = nt * 2 + wc;
    #pragma unroll
    for (int i = 0; i < 4; ++i)
      #pragma unroll
      for (int r = 0; r < 4; ++r) {
        float s = 0.f, ss = 0.f;
        #pragma unroll
        for (int j = 0; j < 4; ++j) {
          float v = acc[i][j][r];
          s += v; ss += v * v;
        }
        #pragma unroll
        for (int mk = 1; mk < 16; mk <<= 1) {
          s  += __shfl_xor(s,  mk, 64);
          ss += __shfl_xor(ss, mk, 64);
        }
        if (myr == i * 4 + r) {
          const int row = m0 + wr * 64 + i * 16 + kq * 4 + r;
          psum[(size_t)row * PW + pcol] = s;
          psq [(size_t)row * PW + pcol] = ss;
        }
      }
  }
}

// ---------------------------------------------------------------------------
// Fused lerp-scan + causal dwconv3. vaT[2D][M] channel-major (theta->v already
// tanh'd by G1 epilogue). 8 channels x 32 chunks of 32 steps per block.
// ---------------------------------------------------------------------------
__global__ __launch_bounds__(256) void scanconv(
    const float* __restrict__ vaT, const float* __restrict__ cw,
    const float* __restrict__ cb, _Float16* __restrict__ z16,
    int S, int D, int M)
{
  const int dl = threadIdx.x & 7;                // channel in block
  const int c  = threadIdx.x >> 3;               // chunk 0..31
  const int ch = blockIdx.x * 8 + dl;
  const int b = ch >> 10, d = ch & 1023;
  const int CH = S / 32;                         // 32
  const float* vrow = vaT + (size_t)d * M + b * S;
  const float* arow = vaT + (size_t)(D + d) * M + b * S;
  const int s0 = c * CH;

  float A = 1.f, Bv = 0.f, Apm = 1.f, Bpm = 0.f;
  for (int t = 0; t < CH; t += 4) {
    f32x4 v4 = *(const f32x4*)&vrow[s0 + t];
    f32x4 a4 = *(const f32x4*)&arow[s0 + t];
    #pragma unroll
    for (int r = 0; r < 4; ++r) {
      if (t + r == CH - 1) { Apm = A; Bpm = Bv; }
      float na = 1.f - a4[r];
      A *= na;
      Bv = Bv * na + a4[r] * v4[r];
    }
  }
  __shared__ float Asm[32][9], Bsm[32][9], Aps[32][9], Bps[32][9];
  Asm[c][dl] = A; Bsm[c][dl] = Bv; Aps[c][dl] = Apm; Bps[c][dl] = Bpm;
  __syncthreads();
  if (threadIdx.x < 8) {                         // serial exclusive prefix
    float run = 0.f;
    for (int cc = 0; cc < 32; ++cc) {
      float A_ = Asm[cc][dl], B_ = Bsm[cc][dl];
      Bsm[cc][dl] = run;                         // h before chunk cc
      run = A_ * run + B_;
    }
  }
  __syncthreads();
  float hm1 = Bsm[c][dl];
  float hm2 = (c == 0) ? 0.f
            : (Aps[c - 1][dl] * Bsm[c - 1][dl] + Bps[c - 1][dl]);

  const float w0 = cw[d * 3 + 0], w1 = cw[d * 3 + 1], w2 = cw[d * 3 + 2];
  const float bc = cb[d];
  for (int t = 0; t < CH; t += 4) {
    f32x4 v4 = *(const f32x4*)&vrow[s0 + t];
    f32x4 a4 = *(const f32x4*)&arow[s0 + t];
    #pragma unroll
    for (int r = 0; r < 4; ++r) {
      float h = hm1 + a4[r] * (v4[r] - hm1);
      float z = h + bc + w0 * hm2 + w1 * hm1 + w2 * h;
      z16[(size_t)(b * S + s0 + t + r) * D + d] = (_Float16)z;
      hm2 = hm1; hm1 = h;
    }
  }
}

// v = p0+p1+bias; delta = rmsnorm(v)*nw; x += delta; o16 = fp16(mode?delta:x)
__global__ __launch_bounds__(256) void rms_fuse(
    const float* __restrict__ p, const float* __restrict__ bias,
    const float* __restrict__ nw, float* __restrict__ x,
    _Float16* __restrict__ o16, int D, int mode, size_t MN)
{
  const size_t base = (size_t)blockIdx.x * D;
  float vloc[4]; float ss = 0.f;
  #pragma unroll
  for (int q = 0; q < 4; ++q) {
    int d = threadIdx.x + q * 256;
    float v = p[base + d] + p[MN + base + d] + bias[d];
    vloc[q] = v; ss += v * v;
  }
  ss = block_sum256(ss);
  float r = 1.f / sqrtf(ss / D + 1e-8f);
  #pragma unroll
  for (int q = 0; q < 4; ++q) {
    int d = threadIdx.x + q * 256;
    float delta = vloc[q] * r * nw[d];
    float xn = x[base + d] + delta;
    x[base + d] = xn;
    o16[base + d] = (_Float16)(mode ? delta : xn);
  }
}

// x += p0+p1 (split-K partials of delta@plastic); x16 = fp16(x)
__global__ __launch_bounds__(256) void xupd(
    const float* __restrict__ p, float* __restrict__ x,
    _Float16* __restrict__ x16, size_t MN)
{
  size_t i = (size_t)blockIdx.x * 256 + threadIdx.x;
  if (i >= MN) return;
  float xn = x[i] + p[i] + p[MN + i];
  x[i] = xn;
  x16[i] = (_Float16)xn;
}

__global__ __launch_bounds__(256) void embed_norm(
    const int* __restrict__ ids, const float* __restrict__ emb,
    const float* __restrict__ pos,
    float* __restrict__ x, _Float16* __restrict__ x16, int S, int D)
{
  const int rowi = blockIdx.x;
  const int s = rowi % S;
  const int tok = ids[rowi];
  const size_t eb = (size_t)tok * D, pb = (size_t)s * D, xb = (size_t)rowi * D;
  float vloc[4]; float ss = 0.f;
  #pragma unroll
  for (int q = 0; q < 4; ++q) {
    int d = threadIdx.x + q * 256;
    float v = emb[eb + d] + pos[pb + d];
    vloc[q] = v; ss += v * v;
  }
  ss = block_sum256(ss);
  float r = 1.f / fmaxf(sqrtf(ss), 1e-12f);
  #pragma unroll
  for (int q = 0; q < 4; ++q) {
    int d = threadIdx.x + q * 256;
    float v = vloc[q] * r;
    x[xb + d] = v;
    x16[xb + d] = (_Float16)v;
  }
}

__global__ __launch_bounds__(256) void final_norm(
    const float* __restrict__ x, const float* __restrict__ w,
    _Float16* __restrict__ xf, int D)
{
  const size_t base = (size_t)blockIdx.x * D;
  float s1 = 0.f, s2 = 0.f;
  float vloc[4], wloc[4];
  #pragma unroll
  for (int q = 0; q < 4; ++q) {
    int d = threadIdx.x + q * 256;
    float v = x[base + d], ww = w[d];
    vloc[q] = v; wloc[q] = ww;
    s1 += v * v; s2 += v * ww * v * ww;
  }
  s1 = block_sum256(s1);
  s2 = block_sum256(s2);
  float r1 = 1.f / sqrtf(s1 / D + 1e-8f);
  float m2 = r1 * r1 * (s2 / D);
  float r2 = 1.f / sqrtf(m2 + 1e-8f);
  float sc = r1 * r2 * 0.8f;
  #pragma unroll
  for (int q = 0; q < 4; ++q) {
    int d = threadIdx.x + q * 256;
    xf[base + d] = (_Float16)(vloc[q] * wloc[q] * sc);
  }
}

__global__ __launch_bounds__(256) void reduce_scale(
    const float* __restrict__ psum, const float* __restrict__ psq,
    float* __restrict__ scale, int PW, int V)
{
  const int row = blockIdx.x;
  float s = 0.f, q = 0.f;
  for (int j = threadIdx.x; j < PW; j += 256) {
    s += psum[(size_t)row * PW + j];
    q += psq [(size_t)row * PW + j];
  }
  s = block_sum256(s);
  q = block_sum256(q);
  float mean = s / V;
  float var = (q - (float)V * mean * mean) / (float)(V - 1);
  var = fmaxf(var, 0.f);
  if (threadIdx.x == 0) scale[row] = 1.f / fmaxf(sqrtf(var), 1.f);
}

__global__ __launch_bounds__(256) void fix_apply(
    float* __restrict__ out, const float* __restrict__ scale, int V)
{
  const int row = blockIdx.y;
  const int j = (blockIdx.x * 256 + threadIdx.x) * 4;
  if (j >= V) return;
  const float sc = scale[row];
  f32x4 v = *(f32x4*)&out[(size_t)row * V + j];
  #pragma unroll
  for (int t = 0; t < 4; ++t)
    v[t] = fminf(fmaxf(v[t] * sc, -10.f), 10.f);
  *(f32x4*)&out[(size_t)row * V + j] = v;
}

// W[K,N] fp32 -> WT[N,K] fp16 (transposed), batched over blockIdx.z
__global__ void tsplit16(const float* __restrict__ W, _Float16* __restrict__ WT,
                         int K, int N)
{
  __shared__ float t[32][33];
  const size_t bo = (size_t)blockIdx.z * K * N;
  const int tx = threadIdx.x, ty = threadIdx.y;
  #pragma unroll
  for (int i = 0; i < 32; i += 8) {
    int kk = blockIdx.y * 32 + ty + i;
    int nn = blockIdx.x * 32 + tx;
    t[ty + i][tx] = W[bo + (size_t)kk * N + nn];
  }
  __syncthreads();
  #pragma unroll
  for (int i = 0; i < 32; i += 8) {
    int nn = blockIdx.x * 32 + ty + i;
    int kk = blockIdx.y * 32 + tx;
    WT[bo + (size_t)nn * K + kk] = (_Float16)t[tx][ty + i];
  }
}

__global__ void cvt_f16(const float* __restrict__ in, _Float16* __restrict__ o, size_t n)
{
  for (size_t i = (size_t)blockIdx.x * 256 + threadIdx.x; i < n;
       i += (size_t)gridDim.x * 256)
    o[i] = (_Float16)in[i];
}

// ---------------------------------------------------------------------------
extern "C" void kernel_launch(void* const* d_in, const int* in_sizes, int n_in,
                              void* d_out, int out_size, void* d_ws, size_t ws_size,
                              hipStream_t stream)
{
  (void)in_sizes; (void)n_in; (void)out_size; (void)ws_size;
  const int*   ids = (const int*)  d_in[0];
  const float* emb = (const float*)d_in[1];
  const float* pos = (const float*)d_in[2];
  const float* kw  = (const float*)d_in[3];
  const float* cw  = (const float*)d_in[4];
  const float* cb  = (const float*)d_in[5];
  const float* w1  = (const float*)d_in[6];
  const float* b1  = (const float*)d_in[7];
  const float* w2  = (const float*)d_in[8];
  const float* b2  = (const float*)d_in[9];
  const float* nw  = (const float*)d_in[10];
  const float* pl  = (const float*)d_in[11];
  const float* fnw = (const float*)d_in[12];
  float* out = (float*)d_out;

  constexpr int B = 2, S = 1024, D = 1024, L = 8, V = 32000;
  constexpr int M = B * S;
  const size_t MN = (size_t)M * D;

  size_t off = 0;
  auto alloc = [&](size_t bytes) {
    char* p = (char*)d_ws + off;
    off += (bytes + 255) & ~(size_t)255;
    return (void*)p;
  };
  _Float16* kwT  = (_Float16*)alloc((size_t)L * 2 * D * D * 2);
  _Float16* w1T  = (_Float16*)alloc((size_t)L * 2 * D * D * 2);
  _Float16* w2T  = (_Float16*)alloc((size_t)L * 2 * D * D * 2);
  _Float16* plT  = (_Float16*)alloc((size_t)4 * D * D * 2);
  _Float16* emb16 = (_Float16*)alloc((size_t)V * D * 2);
  float* x    = (float*)alloc(MN * 4);
  _Float16* x16 = (_Float16*)alloc(MN * 2);
  float* vaT  = (float*)alloc((size_t)M * 2 * D * 4);   // [2D][M]
  float* pbuf = (float*)alloc(2 * MN * 4);              // split-K partials
  _Float16* z16 = (_Float16*)alloc(MN * 2);
  _Float16* u16 = (_Float16*)alloc((size_t)M * 2 * D * 2);
  _Float16* d16 = (_Float16*)alloc(MN * 2);
  _Float16* xf16 = (_Float16*)alloc(MN * 2);

  // head stats overlay vaT (free at head time): PW = V/64 = 500
  const int PW = V >> 6;
  float* psum  = vaT;
  float* psq   = vaT + (size_t)M * PW;
  float* scale = psq + (size_t)M * PW;

  // ---- weight prep ----
  {
    dim3 tb(32, 8);
    tsplit16<<<dim3(2 * D / 32, D / 32, L), tb, 0, stream>>>(kw, kwT, D, 2 * D);
    tsplit16<<<dim3(2 * D / 32, D / 32, L), tb, 0, stream>>>(w1, w1T, D, 2 * D);
    tsplit16<<<dim3(D / 32, 2 * D / 32, L), tb, 0, stream>>>(w2, w2T, 2 * D, D);
    tsplit16<<<dim3(D / 32, D / 32, 4),     tb, 0, stream>>>(pl, plT, D, D);
    cvt_f16<<<4096, 256, 0, stream>>>(emb, emb16, (size_t)V * D);
  }

  embed_norm<<<M, 256, 0, stream>>>(ids, emb, pos, x, x16, S, D);

  for (int i = 0; i < L; ++i) {
    const _Float16* kwi = kwT + (size_t)i * 2 * D * D;
    const _Float16* w1i = w1T + (size_t)i * 2 * D * D;
    const _Float16* w2i = w2T + (size_t)i * 2 * D * D;

    // G1: res = x@kw -> vaT channel-major, v=tanh*pi | a=sigmoid
    gemm4<1, 1><<<(M / 128) * (2 * D / 128), 256, 0, stream>>>(
        x16, kwi, M, 2 * D, D, vaT, nullptr, nullptr, nullptr, nullptr, D);

    scanconv<<<B * D / 8, 256, 0, stream>>>(
        vaT, cw + (size_t)i * D * 3, cb + (size_t)i * D, z16, S, D, M);

    // G2: u = silu(z@w1 + b1) -> fp16
    gemm4<2, 1><<<(M / 128) * (2 * D / 128), 256, 0, stream>>>(
        z16, w1i, M, 2 * D, D, nullptr, u16, b1 + (size_t)i * 2 * D,
        nullptr, nullptr, 0);

    // G3: hf partials = u@w2 (split-K x2)
    gemm4<5, 2><<<(M / 128) * (D / 128) * 2, 256, 0, stream>>>(
        u16, w2i, M, D, 2 * D, pbuf, nullptr, nullptr, nullptr, nullptr, 0);

    const int mode = (i >= L - 4) ? 1 : 0;
    rms_fuse<<<M, 256, 0, stream>>>(pbuf, b2 + (size_t)i * D, nw + (size_t)i * D,
                                    x, mode ? d16 : x16, D, mode, MN);
    if (mode) {
      const _Float16* pli = plT + (size_t)(i - 4) * D * D;
      // G4: partials = delta @ plastic (split-K x2)
      gemm4<5, 2><<<(M / 128) * (D / 128) * 2, 256, 0, stream>>>(
          d16, pli, M, D, D, pbuf, nullptr, nullptr, nullptr, nullptr, 0);
      xupd<<<(int)(MN / 256), 256, 0, stream>>>(pbuf, x, x16, MN);
    }
  }

  final_norm<<<M, 256, 0, stream>>>(x, fnw, xf16, D);

  // LM head: logits = xf @ emb^T + fused row stats
  gemm4<0, 1><<<(M / 128) * (V / 128), 256, 0, stream>>>(
      xf16, emb16, M, V, D, out, nullptr, nullptr, psum, psq, 0);

  reduce_scale<<<M, 256, 0, stream>>>(psum, psq, scale, PW, V);
  fix_apply<<<dim3((V / 4 + 255) / 256, M), 256, 0, stream>>>(out, scale, V);
}